// Round 4
// baseline (463.886 us; speedup 1.0000x reference)
//
#include <hip/hip_runtime.h>

// LocalExpansion: out[b,h,(y,x),c,d] = in[b,h,(y+i-3,x+j-3),d], c = i*7+j,
// zero-filled outside the image. Memory-movement kernel: 462 MB write,
// 9.4 MB input logically read 49x (should be cache-resident).
//
// v11 = v10 + bijective chunked XCD swizzle (T1).
// Post-mortem v10: nt stores were neutral (463.0 -> 456.5, ~fill variance).
// Kernel-side time ~164 us = 292 us poison fill subtracted from bench dur.
// 164 us fits 924 MB (462 wr + 462 rd) at ~5.6 TB/s mixed HBM almost exactly
// -> reads really do go to HBM at full volume. Mechanism is NOT simple
// write-eviction (nt would have helped): it's (a) round-robin dispatch puts
// every input line's consumers on all 8 XCDs -> 8 private-L2 copies, and
// (b) each line's reuse window (~220 consecutive block ids: +-3 output rows
// x 49 c) is smeared across XCDs while each 4 MiB L2 recycles every ~5 us
// under its ~790 GB/s write-stream share. Fix: chunked swizzle so XCD k
// owns contiguous logical blocks [k*3528, (k+1)*3528) -- input line fetched
// by ONE XCD, reuse window fits that XCD's ~256 co-resident blocks.
// 28224 % 8 == 0 -> the simple swizzle is bijective (no m204 variant needed).
//
// Structure otherwise unchanged from v8/v10: 4-deep ILP per wave,
// block-contiguous unroll; all 4 branchless loads (clamped addr + select)
// issue before the first store; every store instruction is 256-lane
// contiguous; each logical block writes one 16 KB contiguous span;
// nt stores keep the 462 MB write stream evict-first in L2.

#define KH 7
#define KW 7
#define HEIGHT 48
#define WIDTH 48
#define DDIM 64
#define NPIX (HEIGHT * WIDTH)   // 2304
#define KK (KH * KW)            // 49
#define UNROLL 4
#define NXCD 8

typedef __attribute__((ext_vector_type(4))) float nt_float4;

__global__ __launch_bounds__(256) void local_expansion_kernel(
    const float* __restrict__ in, float* __restrict__ out) {
    // Chunked XCD swizzle: hardware dispatch id round-robins XCDs (id % 8),
    // so logical block = (id % 8) * (nwg/8) + id / 8 gives XCD k a
    // contiguous chunk of the output (and a contiguous input slice).
    int cpx = gridDim.x >> 3;  // 28224/8 = 3528, exact
    int bid = (blockIdx.x & (NXCD - 1)) * cpx + (blockIdx.x >> 3);
    int base4 = bid * (256 * UNROLL) + threadIdx.x;

    nt_float4 v[UNROLL];

#pragma unroll
    for (int u = 0; u < UNROLL; ++u) {
        int idx4 = base4 + u * 256;

        // idx4 = ((bh*NPIX + n)*KK + c)*16 + d4
        int d4   = idx4 & 15;
        int rem  = idx4 >> 4;
        int c    = rem % KK;
        int rem2 = rem / KK;
        int n    = rem2 % NPIX;
        int bh   = rem2 / NPIX;

        int y = n / WIDTH;
        int x = n - y * WIDTH;
        int i = c / KW;
        int j = c - i * KW;

        int sy = y + i - (KH - 1) / 2;
        int sx = x + j - (KW - 1) / 2;

        bool inb = ((unsigned)sy < (unsigned)HEIGHT) & ((unsigned)sx < (unsigned)WIDTH);

        // Branchless: clamp to a valid address, load unconditionally, select.
        int syc = min(max(sy, 0), HEIGHT - 1);
        int sxc = min(max(sx, 0), WIDTH - 1);
        int in4 = (bh * NPIX + syc * WIDTH + sxc) * (DDIM / 4) + d4;

        nt_float4 t = ((const nt_float4*)in)[in4];
        nt_float4 z = (nt_float4)(0.f);
        v[u] = inb ? t : z;
    }

#pragma unroll
    for (int u = 0; u < UNROLL; ++u) {
        // Output is write-once, never re-read: non-temporal store keeps the
        // 462 MB stream evict-first in L2 so the input stays cache-resident.
        __builtin_nontemporal_store(v[u], ((nt_float4*)out) + base4 + u * 256);
    }
}

extern "C" void kernel_launch(void* const* d_in, const int* in_sizes, int n_in,
                              void* d_out, int out_size, void* d_ws, size_t ws_size,
                              hipStream_t stream) {
    const float* x = (const float*)d_in[0];
    float* out = (float*)d_out;

    // out_size = 115,605,504 floats -> 28,901,376 float4s; /(256*4) = 28,224 exact
    int total4 = out_size / 4;
    int blocks = total4 / (256 * UNROLL);
    local_expansion_kernel<<<dim3(blocks), 256, 0, stream>>>(x, out);
}